// Round 1
// 718.640 us; speedup vs baseline: 1.5017x; 1.5017x over previous
//
#include <hip/hip_runtime.h>
#include <hip/hip_bf16.h>

#define Bsz  16384
#define Din  1024
#define Dout 1024
#define Hdim 2048
#define Ecnt 8
#define CNT_PAD 32   // pad expert counters to 128 B apart: no single-cacheline atomic convoy

typedef _Float16 f16;
typedef _Float16 f16x8 __attribute__((ext_vector_type(8)));
typedef _Float16 f16x4 __attribute__((ext_vector_type(4)));
typedef float    f32x4 __attribute__((ext_vector_type(4)));

#define AS_GLOBAL __attribute__((address_space(1)))
#define AS_LDS    __attribute__((address_space(3)))

__device__ __forceinline__ void async_copy16(const void* gptr, void* lptr) {
    __builtin_amdgcn_global_load_lds(
        (const AS_GLOBAL unsigned int*)gptr,
        (AS_LDS unsigned int*)lptr, 16, 0, 0);
}

// ---------------- fp32 -> fp16 cast ----------------
__global__ __launch_bounds__(256) void cast_kernel(
    const float* __restrict__ in, f16* __restrict__ out)
{
    int i = (blockIdx.x * 256 + threadIdx.x) * 4;
    float4 v = *(const float4*)(in + i);
    f16x4 o;
    o.x = (f16)v.x; o.y = (f16)v.y; o.z = (f16)v.z; o.w = (f16)v.w;
    *(f16x4*)(out + i) = o;
}

// ---------------- Router: logits -> softmax -> top-2 -> buckets ----------------
// 32 tokens/block (8 per wave). Bucket insertion is two-level:
//   per-block LDS histogram -> ONE padded global atomic per (block, expert).
// This replaces 32768 returning atomics on one cacheline (the old 380 us convoy)
// with 4096 atomics spread over 8 cachelines.
__global__ __launch_bounds__(256) void router_kernel(
    const float* __restrict__ x, const float* __restrict__ rW,
    const float* __restrict__ rb, float* __restrict__ probs_out,
    int* __restrict__ cnt, int* __restrict__ bucket, float* __restrict__ gates)
{
    __shared__ float s_rw[Ecnt * Din];   // 32 KiB
    __shared__ int   s_e[64];            // per-entry expert id   (32 tokens x 2)
    __shared__ float s_g[64];            // per-entry gate
    __shared__ int   s_lpos[64];         // local position within expert
    __shared__ int   s_lcnt[Ecnt];
    __shared__ int   s_base[Ecnt];

    int t = threadIdx.x;
    if (t < Ecnt) s_lcnt[t] = 0;
    for (int i = t; i < Ecnt * Din; i += 256) s_rw[i] = rW[i];
    __syncthreads();

    int wid = t >> 6, lane = t & 63;

    float rbv[8];
    #pragma unroll
    for (int e = 0; e < 8; e++) rbv[e] = rb[e];

    #pragma unroll 2
    for (int tt = 0; tt < 8; tt++) {
        int li = wid * 8 + tt;                   // local token 0..31
        int token = blockIdx.x * 32 + li;
        const float* xrow = x + (size_t)token * Din;

        float acc[8] = {0,0,0,0,0,0,0,0};
        #pragma unroll
        for (int i = 0; i < 4; i++) {
            float4 xv = *(const float4*)(xrow + i * 256 + lane * 4);
            #pragma unroll
            for (int e = 0; e < 8; e++) {
                float4 wv = *(const float4*)(s_rw + e * Din + i * 256 + lane * 4);
                acc[e] += xv.x * wv.x + xv.y * wv.y + xv.z * wv.z + xv.w * wv.w;
            }
        }
        #pragma unroll
        for (int e = 0; e < 8; e++) {
            #pragma unroll
            for (int m = 1; m < 64; m <<= 1) acc[e] += __shfl_xor(acc[e], m, 64);
        }

        float p[8], mx = -1e30f;
        #pragma unroll
        for (int e = 0; e < 8; e++) { p[e] = acc[e] + rbv[e]; mx = fmaxf(mx, p[e]); }
        float s = 0.f;
        #pragma unroll
        for (int e = 0; e < 8; e++) { p[e] = expf(p[e] - mx); s += p[e]; }
        float inv = 1.f / s;
        #pragma unroll
        for (int e = 0; e < 8; e++) p[e] *= inv;

        if (lane == 0) {
            float* po = probs_out + (size_t)token * Ecnt;
            #pragma unroll
            for (int e = 0; e < 8; e++) po[e] = p[e];
            int i0 = 0; float v0 = p[0];
            #pragma unroll
            for (int e = 1; e < 8; e++) if (p[e] > v0) { v0 = p[e]; i0 = e; }
            int i1 = -1; float v1 = -1e30f;
            #pragma unroll
            for (int e = 0; e < 8; e++) if (e != i0 && p[e] > v1) { v1 = p[e]; i1 = e; }
            float invs = 1.f / (v0 + v1);
            s_e[2 * li]     = i0;  s_g[2 * li]     = v0 * invs;
            s_e[2 * li + 1] = i1;  s_g[2 * li + 1] = v1 * invs;
        }
    }
    __syncthreads();

    // local positions via LDS atomics (fast, no global contention)
    if (t < 64) s_lpos[t] = atomicAdd(&s_lcnt[s_e[t]], 1);
    __syncthreads();
    // one padded global atomic per (block, expert)
    if (t < Ecnt) s_base[t] = atomicAdd(&cnt[t * CNT_PAD], s_lcnt[t]);
    __syncthreads();
    if (t < 64) {
        int e = s_e[t];
        int pos = s_base[e] + s_lpos[t];
        int li = t >> 1;
        int token = blockIdx.x * 32 + li;
        bucket[e * Bsz + pos] = token * 2 + (t & 1);
        gates [e * Bsz + pos] = s_g[t];
    }
}

// ---------------- MFMA grouped GEMM (m97 structure) ----------------
// G1: h[r,:] = relu(x_f16[r>>1,:] @ W1[e].T + b1[e]) -> hbuf (f16)
// G2: out[r>>1,:] += gate[r] * (hbuf[r,:] @ W2[e].T + b2[e])   (atomicAdd)
template<int Kd, bool G1>
__global__ __launch_bounds__(256) void moe_gemm(
    const f16* __restrict__ A, const f16* __restrict__ Wt,
    const float* __restrict__ bias, const int* __restrict__ cnt,
    const int* __restrict__ bucket, const float* __restrict__ gates,
    f16* __restrict__ hbuf, float* __restrict__ out, int Ndim)
{
    int e = blockIdx.z;
    int count = min(cnt[e * CNT_PAD], Bsz);
    int m0 = blockIdx.y * 128;
    if (m0 >= count) return;
    int n0 = blockIdx.x * 128;

    __shared__ alignas(16) f16 As[128 * 32];
    __shared__ alignas(16) f16 Bs[128 * 32];
    __shared__ int   s_rows[128];
    __shared__ float s_gates[128];

    int t = threadIdx.x;
    if (t < 128) {
        int pos = min(m0 + t, count - 1);
        s_rows[t] = bucket[e * Bsz + pos];
        if constexpr (!G1) s_gates[t] = gates[e * Bsz + pos];
    }
    __syncthreads();

    int wave = t >> 6, lane = t & 63;
    int scol = (lane & 3) * 8;            // f16 elems within row (16 B chunks)

    // per-lane global source pointers: 2 staging instrs each for A and B
    const f16* agp[2];
    const f16* bgp[2];
    #pragma unroll
    for (int j = 0; j < 2; j++) {
        int srow = wave * 32 + j * 16 + (lane >> 2);
        int r = s_rows[srow];
        size_t arow = G1 ? (size_t)(r >> 1) : (size_t)r;
        agp[j] = A + arow * Kd + scol;
        bgp[j] = Wt + ((size_t)e * Ndim + (n0 + srow)) * (size_t)Kd + scol;
    }

    int m_w = (wave >> 1) * 64;           // wave's 64x64 sub-tile
    int n_w = (wave & 1) * 64;
    int frow = lane & 15;
    int fk   = (lane >> 4) * 8;

    f32x4 acc[4][4] = {};

    for (int k0 = 0; k0 < Kd; k0 += 32) {
        #pragma unroll
        for (int j = 0; j < 2; j++) {
            async_copy16(agp[j], As + (wave * 32 + j * 16) * 32);
            async_copy16(bgp[j], Bs + (wave * 32 + j * 16) * 32);
            agp[j] += 32; bgp[j] += 32;
        }
        __syncthreads();   // compiler drains vmcnt before s_barrier

        f16x8 af[4], bfr[4];
        #pragma unroll
        for (int i = 0; i < 4; i++) {
            af[i]  = *(const f16x8*)(As + (m_w + i * 16 + frow) * 32 + fk);
            bfr[i] = *(const f16x8*)(Bs + (n_w + i * 16 + frow) * 32 + fk);
        }
        #pragma unroll
        for (int i = 0; i < 4; i++)
            #pragma unroll
            for (int jj = 0; jj < 4; jj++)
                acc[i][jj] = __builtin_amdgcn_mfma_f32_16x16x32_f16(
                    af[i], bfr[jj], acc[i][jj], 0, 0, 0);
        __syncthreads();   // frag reads done before next stage overwrites
    }

    // epilogue: D row = m = (lane>>4)*4 + reg (+16*i), D col = n = lane&15 (+16*jj)
    float bv[4];
    #pragma unroll
    for (int jj = 0; jj < 4; jj++)
        bv[jj] = bias[e * Ndim + n0 + n_w + jj * 16 + frow];

    #pragma unroll
    for (int i = 0; i < 4; i++) {
        int mbase = m_w + i * 16 + (lane >> 4) * 4;
        #pragma unroll
        for (int reg = 0; reg < 4; reg++) {
            int m = mbase + reg;
            if (m0 + m >= count) continue;
            int r = s_rows[m];
            if constexpr (G1) {
                f16* hrow = hbuf + (size_t)r * Hdim;
                #pragma unroll
                for (int jj = 0; jj < 4; jj++) {
                    int n = n0 + n_w + jj * 16 + frow;
                    float v = acc[i][jj][reg] + bv[jj];
                    hrow[n] = (f16)fmaxf(v, 0.f);
                }
            } else {
                int token = r >> 1;
                float g = s_gates[m];
                #pragma unroll
                for (int jj = 0; jj < 4; jj++) {
                    int n = n0 + n_w + jj * 16 + frow;
                    float v = g * (acc[i][jj][reg] + bv[jj]);
                    atomicAdd(&out[(size_t)token * Dout + n], v);
                }
            }
        }
    }
}

extern "C" void kernel_launch(void* const* d_in, const int* in_sizes, int n_in,
                              void* d_out, int out_size, void* d_ws, size_t ws_size,
                              hipStream_t stream) {
    const float* x   = (const float*)d_in[0];
    const float* rW  = (const float*)d_in[1];
    const float* rb  = (const float*)d_in[2];
    const float* W1  = (const float*)d_in[3];
    const float* b1  = (const float*)d_in[4];
    const float* W2  = (const float*)d_in[5];
    const float* b2  = (const float*)d_in[6];
    float* out   = (float*)d_out;
    float* probs = out + (size_t)Bsz * Dout;

    // Workspace layout (bucket/gates are 512 KiB EACH)
    char* ws = (char*)d_ws;
    int*   cnt    = (int*)ws;                            // 8*32*4 = 1 KiB (padded)
    int*   bucket = (int*)(ws + 0x1000);                 // 512 KiB (Ecnt*Bsz*4)
    float* gates  = (float*)(ws + 0x90000);              // 512 KiB
    f16*   x16    = (f16*)(ws + 0x200000);               // 32 MiB
    f16*   w16    = (f16*)(ws + 0x2200000);              // 32 MiB (W1, then W2)
    f16*   hbuf   = (f16*)(ws + 0x4200000);              // 128 MiB
    // total = 0xC200000 = 194 MiB

    hipMemsetAsync(cnt, 0, Ecnt * CNT_PAD * sizeof(int), stream);
    hipMemsetAsync(out, 0, (size_t)Bsz * Dout * sizeof(float), stream);

    cast_kernel<<<(Bsz * Din) / 1024, 256, 0, stream>>>(x, x16);
    cast_kernel<<<(Ecnt * Hdim * Din) / 1024, 256, 0, stream>>>(W1, w16);

    router_kernel<<<Bsz / 32, 256, 0, stream>>>(x, rW, rb, probs, cnt, bucket, gates);

    dim3 g1(Hdim / 128, Bsz / 128, Ecnt);
    moe_gemm<Din, true><<<g1, 256, 0, stream>>>(
        x16, w16, b1, cnt, bucket, gates, hbuf, out, Hdim);

    // W2 cast reuses w16 (stream-ordered after gemm1)
    cast_kernel<<<(Ecnt * Dout * Hdim) / 1024, 256, 0, stream>>>(W2, w16);

    dim3 g2(Dout / 128, Bsz / 128, Ecnt);
    moe_gemm<Hdim, false><<<g2, 256, 0, stream>>>(
        hbuf, w16, b2, cnt, bucket, gates, hbuf, out, Dout);
}

// Round 2
// 706.576 us; speedup vs baseline: 1.5274x; 1.0171x over previous
//
#include <hip/hip_runtime.h>
#include <hip/hip_bf16.h>

#define Bsz  16384
#define Din  1024
#define Dout 1024
#define Hdim 2048
#define Ecnt 8
#define CNT_PAD 32   // pad expert counters to 128 B apart: no single-cacheline atomic convoy

typedef _Float16 f16;
typedef _Float16 f16x8 __attribute__((ext_vector_type(8)));
typedef _Float16 f16x4 __attribute__((ext_vector_type(4)));
typedef float    f32x4 __attribute__((ext_vector_type(4)));

#define AS_GLOBAL __attribute__((address_space(1)))
#define AS_LDS    __attribute__((address_space(3)))

__device__ __forceinline__ void async_copy16(const void* gptr, void* lptr) {
    __builtin_amdgcn_global_load_lds(
        (const AS_GLOBAL unsigned int*)gptr,
        (AS_LDS unsigned int*)lptr, 16, 0, 0);
}

// ---------------- fp32 -> fp16 cast ----------------
__global__ __launch_bounds__(256) void cast_kernel(
    const float* __restrict__ in, f16* __restrict__ out)
{
    int i = (blockIdx.x * 256 + threadIdx.x) * 4;
    float4 v = *(const float4*)(in + i);
    f16x4 o;
    o.x = (f16)v.x; o.y = (f16)v.y; o.z = (f16)v.z; o.w = (f16)v.w;
    *(f16x4*)(out + i) = o;
}

// ---------------- Router: logits -> softmax -> top-2 -> buckets ----------------
// 32 tokens/block (8 per wave). Two-level bucket insertion:
//   per-block LDS histogram -> ONE padded global atomic per (block, expert).
__global__ __launch_bounds__(256) void router_kernel(
    const float* __restrict__ x, const float* __restrict__ rW,
    const float* __restrict__ rb, float* __restrict__ probs_out,
    int* __restrict__ cnt, int* __restrict__ bucket, float* __restrict__ gates)
{
    __shared__ float s_rw[Ecnt * Din];   // 32 KiB
    __shared__ int   s_e[64];            // per-entry expert id   (32 tokens x 2)
    __shared__ float s_g[64];            // per-entry gate
    __shared__ int   s_lpos[64];         // local position within expert
    __shared__ int   s_lcnt[Ecnt];
    __shared__ int   s_base[Ecnt];

    int t = threadIdx.x;
    if (t < Ecnt) s_lcnt[t] = 0;
    for (int i = t; i < Ecnt * Din; i += 256) s_rw[i] = rW[i];
    __syncthreads();

    int wid = t >> 6, lane = t & 63;

    float rbv[8];
    #pragma unroll
    for (int e = 0; e < 8; e++) rbv[e] = rb[e];

    #pragma unroll 2
    for (int tt = 0; tt < 8; tt++) {
        int li = wid * 8 + tt;                   // local token 0..31
        int token = blockIdx.x * 32 + li;
        const float* xrow = x + (size_t)token * Din;

        float acc[8] = {0,0,0,0,0,0,0,0};
        #pragma unroll
        for (int i = 0; i < 4; i++) {
            float4 xv = *(const float4*)(xrow + i * 256 + lane * 4);
            #pragma unroll
            for (int e = 0; e < 8; e++) {
                float4 wv = *(const float4*)(s_rw + e * Din + i * 256 + lane * 4);
                acc[e] += xv.x * wv.x + xv.y * wv.y + xv.z * wv.z + xv.w * wv.w;
            }
        }
        #pragma unroll
        for (int e = 0; e < 8; e++) {
            #pragma unroll
            for (int m = 1; m < 64; m <<= 1) acc[e] += __shfl_xor(acc[e], m, 64);
        }

        float p[8], mx = -1e30f;
        #pragma unroll
        for (int e = 0; e < 8; e++) { p[e] = acc[e] + rbv[e]; mx = fmaxf(mx, p[e]); }
        float s = 0.f;
        #pragma unroll
        for (int e = 0; e < 8; e++) { p[e] = expf(p[e] - mx); s += p[e]; }
        float inv = 1.f / s;
        #pragma unroll
        for (int e = 0; e < 8; e++) p[e] *= inv;

        if (lane == 0) {
            float* po = probs_out + (size_t)token * Ecnt;
            #pragma unroll
            for (int e = 0; e < 8; e++) po[e] = p[e];
            int i0 = 0; float v0 = p[0];
            #pragma unroll
            for (int e = 1; e < 8; e++) if (p[e] > v0) { v0 = p[e]; i0 = e; }
            int i1 = -1; float v1 = -1e30f;
            #pragma unroll
            for (int e = 0; e < 8; e++) if (e != i0 && p[e] > v1) { v1 = p[e]; i1 = e; }
            float invs = 1.f / (v0 + v1);
            s_e[2 * li]     = i0;  s_g[2 * li]     = v0 * invs;
            s_e[2 * li + 1] = i1;  s_g[2 * li + 1] = v1 * invs;
        }
    }
    __syncthreads();

    if (t < 64) s_lpos[t] = atomicAdd(&s_lcnt[s_e[t]], 1);
    __syncthreads();
    if (t < Ecnt) s_base[t] = atomicAdd(&cnt[t * CNT_PAD], s_lcnt[t]);
    __syncthreads();
    if (t < 64) {
        int e = s_e[t];
        int pos = s_base[e] + s_lpos[t];
        int li = t >> 1;
        int token = blockIdx.x * 32 + li;
        bucket[e * Bsz + pos] = token * 2 + (t & 1);
        gates [e * Bsz + pos] = s_g[t];
    }
}

// ---------------- MFMA grouped GEMM (T3 minimum-2-phase pipeline) ----------------
// Double-buffered LDS, ONE barrier per K-step:
//   { ds_read cur -> prefetch next into cur^1 -> MFMA -> syncthreads }
// The syncthreads' conservative vmcnt(0)+lgkmcnt(0) drain IS the recipe's
// "vmcnt(0); barrier" — prefetch latency hides under ds_read+MFMA instead of
// being serially drained before compute (the old 2-barrier structure).
// G1: h[r,:] = relu(x_f16[r>>1,:] @ W1[e].T + b1[e]) -> hbuf (f16)
// G2: out[r>>1,:] += gate[r] * (hbuf[r,:] @ W2[e].T + b2[e])   (atomicAdd)
template<int Kd, bool G1>
__global__ __launch_bounds__(256) void moe_gemm(
    const f16* __restrict__ A, const f16* __restrict__ Wt,
    const float* __restrict__ bias, const int* __restrict__ cnt,
    const int* __restrict__ bucket, const float* __restrict__ gates,
    f16* __restrict__ hbuf, float* __restrict__ out, int Ndim)
{
    int e = blockIdx.z;
    int count = min(cnt[e * CNT_PAD], Bsz);
    int m0 = blockIdx.y * 128;
    if (m0 >= count) return;
    int n0 = blockIdx.x * 128;

    __shared__ alignas(16) f16 As[2][128 * 32];   // 2 x 8 KiB
    __shared__ alignas(16) f16 Bs[2][128 * 32];   // 2 x 8 KiB
    __shared__ int   s_rows[128];
    __shared__ float s_gates[128];

    int t = threadIdx.x;
    if (t < 128) {
        int pos = min(m0 + t, count - 1);
        s_rows[t] = bucket[e * Bsz + pos];
        if constexpr (!G1) s_gates[t] = gates[e * Bsz + pos];
    }
    __syncthreads();

    int wave = t >> 6, lane = t & 63;
    int scol = (lane & 3) * 8;            // f16 elems within row (16 B chunks)

    // per-lane global source pointers: 2 staging instrs each for A and B
    const f16* agp[2];
    const f16* bgp[2];
    #pragma unroll
    for (int j = 0; j < 2; j++) {
        int srow = wave * 32 + j * 16 + (lane >> 2);
        int r = s_rows[srow];
        size_t arow = G1 ? (size_t)(r >> 1) : (size_t)r;
        agp[j] = A + arow * Kd + scol;
        bgp[j] = Wt + ((size_t)e * Ndim + (n0 + srow)) * (size_t)Kd + scol;
    }

    int m_w = (wave >> 1) * 64;           // wave's 64x64 sub-tile
    int n_w = (wave & 1) * 64;
    int frow = lane & 15;
    int fk   = (lane >> 4) * 8;

    f32x4 acc[4][4] = {};

    // prologue: stage tile 0 into buffer 0
    #pragma unroll
    for (int j = 0; j < 2; j++) {
        async_copy16(agp[j], &As[0][(wave * 32 + j * 16) * 32]);
        async_copy16(bgp[j], &Bs[0][(wave * 32 + j * 16) * 32]);
        agp[j] += 32; bgp[j] += 32;
    }
    __syncthreads();   // vmcnt(0) drain: tile 0 resident

    int cur = 0;
    for (int k0 = 0; k0 < Kd; k0 += 32) {
        // 1) issue ds_reads of current buffer (before any new gload_lds:
        //    no LDS-alias ordering hazard for the compiler to be paranoid about)
        f16x8 af[4], bfr[4];
        #pragma unroll
        for (int i = 0; i < 4; i++) {
            af[i]  = *(const f16x8*)(&As[cur][(m_w + i * 16 + frow) * 32 + fk]);
            bfr[i] = *(const f16x8*)(&Bs[cur][(n_w + i * 16 + frow) * 32 + fk]);
        }
        // 2) prefetch next K-tile into the other buffer; latency hides under MFMA
        if (k0 + 32 < Kd) {
            #pragma unroll
            for (int j = 0; j < 2; j++) {
                async_copy16(agp[j], &As[cur ^ 1][(wave * 32 + j * 16) * 32]);
                async_copy16(bgp[j], &Bs[cur ^ 1][(wave * 32 + j * 16) * 32]);
                agp[j] += 32; bgp[j] += 32;
            }
        }
        // 3) MFMA (compiler auto-inserts lgkmcnt waits on af/bfr uses)
        __builtin_amdgcn_s_setprio(1);
        #pragma unroll
        for (int i = 0; i < 4; i++)
            #pragma unroll
            for (int jj = 0; jj < 4; jj++)
                acc[i][jj] = __builtin_amdgcn_mfma_f32_16x16x32_f16(
                    af[i], bfr[jj], acc[i][jj], 0, 0, 0);
        __builtin_amdgcn_s_setprio(0);
        // 4) single barrier per K-step: drains prefetch vmcnt + fences buffer reuse
        __syncthreads();
        cur ^= 1;
    }

    // epilogue: D row = m = (lane>>4)*4 + reg (+16*i), D col = n = lane&15 (+16*jj)
    float bv[4];
    #pragma unroll
    for (int jj = 0; jj < 4; jj++)
        bv[jj] = bias[e * Ndim + n0 + n_w + jj * 16 + frow];

    #pragma unroll
    for (int i = 0; i < 4; i++) {
        int mbase = m_w + i * 16 + (lane >> 4) * 4;
        #pragma unroll
        for (int reg = 0; reg < 4; reg++) {
            int m = mbase + reg;
            if (m0 + m >= count) continue;
            int r = s_rows[m];
            if constexpr (G1) {
                f16* hrow = hbuf + (size_t)r * Hdim;
                #pragma unroll
                for (int jj = 0; jj < 4; jj++) {
                    int n = n0 + n_w + jj * 16 + frow;
                    float v = acc[i][jj][reg] + bv[jj];
                    hrow[n] = (f16)fmaxf(v, 0.f);
                }
            } else {
                int token = r >> 1;
                float g = s_gates[m];
                #pragma unroll
                for (int jj = 0; jj < 4; jj++) {
                    int n = n0 + n_w + jj * 16 + frow;
                    float v = g * (acc[i][jj][reg] + bv[jj]);
                    atomicAdd(&out[(size_t)token * Dout + n], v);
                }
            }
        }
    }
}

extern "C" void kernel_launch(void* const* d_in, const int* in_sizes, int n_in,
                              void* d_out, int out_size, void* d_ws, size_t ws_size,
                              hipStream_t stream) {
    const float* x   = (const float*)d_in[0];
    const float* rW  = (const float*)d_in[1];
    const float* rb  = (const float*)d_in[2];
    const float* W1  = (const float*)d_in[3];
    const float* b1  = (const float*)d_in[4];
    const float* W2  = (const float*)d_in[5];
    const float* b2  = (const float*)d_in[6];
    float* out   = (float*)d_out;
    float* probs = out + (size_t)Bsz * Dout;

    // Workspace layout (bucket/gates are 512 KiB EACH)
    char* ws = (char*)d_ws;
    int*   cnt    = (int*)ws;                            // 8*32*4 = 1 KiB (padded)
    int*   bucket = (int*)(ws + 0x1000);                 // 512 KiB (Ecnt*Bsz*4)
    float* gates  = (float*)(ws + 0x90000);              // 512 KiB
    f16*   x16    = (f16*)(ws + 0x200000);               // 32 MiB
    f16*   w16    = (f16*)(ws + 0x2200000);              // 32 MiB (W1, then W2)
    f16*   hbuf   = (f16*)(ws + 0x4200000);              // 128 MiB
    // total = 0xC200000 = 194 MiB

    hipMemsetAsync(cnt, 0, Ecnt * CNT_PAD * sizeof(int), stream);
    hipMemsetAsync(out, 0, (size_t)Bsz * Dout * sizeof(float), stream);

    cast_kernel<<<(Bsz * Din) / 1024, 256, 0, stream>>>(x, x16);
    cast_kernel<<<(Ecnt * Hdim * Din) / 1024, 256, 0, stream>>>(W1, w16);

    router_kernel<<<Bsz / 32, 256, 0, stream>>>(x, rW, rb, probs, cnt, bucket, gates);

    dim3 g1(Hdim / 128, Bsz / 128, Ecnt);
    moe_gemm<Din, true><<<g1, 256, 0, stream>>>(
        x16, w16, b1, cnt, bucket, gates, hbuf, out, Hdim);

    // W2 cast reuses w16 (stream-ordered after gemm1)
    cast_kernel<<<(Ecnt * Dout * Hdim) / 1024, 256, 0, stream>>>(W2, w16);

    dim3 g2(Dout / 128, Bsz / 128, Ecnt);
    moe_gemm<Hdim, false><<<g2, 256, 0, stream>>>(
        hbuf, w16, b2, cnt, bucket, gates, hbuf, out, Dout);
}